// Round 2
// baseline (328.277 us; speedup 1.0000x reference)
//
#include <hip/hip_runtime.h>
#include <hip/hip_bf16.h>
#include <type_traits>

typedef __attribute__((ext_vector_type(8))) short bf16x8;
typedef __attribute__((ext_vector_type(4))) float f32x4;

__device__ __forceinline__ ushort f32_to_bf16(float f) {
  union { float f; unsigned u; } x; x.f = f;
  unsigned r = x.u + 0x7fffu + ((x.u >> 16) & 1u);
  return (ushort)(r >> 16);
}

// fetch 8 consecutive elements as bf16 (converting if fp32 source)
__device__ __forceinline__ void fetch8(const float* g, ushort* r) {
  float4 a = *(const float4*)g;
  float4 b = *(const float4*)(g + 4);
  r[0] = f32_to_bf16(a.x); r[1] = f32_to_bf16(a.y);
  r[2] = f32_to_bf16(a.z); r[3] = f32_to_bf16(a.w);
  r[4] = f32_to_bf16(b.x); r[5] = f32_to_bf16(b.y);
  r[6] = f32_to_bf16(b.z); r[7] = f32_to_bf16(b.w);
}
__device__ __forceinline__ void fetch8(const ushort* g, ushort* r) {
  union { uint4 v; ushort s[8]; } u;
  u.v = *(const uint4*)g;
#pragma unroll
  for (int i = 0; i < 8; ++i) r[i] = u.s[i];
}

// ---------------------------------------------------------------------------
// GEMM: C[M,N] = A[M,K] * B[K,N] (+ fp32 bias), bf16 MFMA compute, fp32 accum.
// TA/TB in {float,ushort(bf16)}, TC in {float,ushort}.
// 128x128 tile, BK=32, 256 threads (2x2 waves, each wave 64x64 = 4x4 MFMA tiles)
// ---------------------------------------------------------------------------
template <typename TA, typename TB, typename TC>
__global__ __launch_bounds__(256) void gemm_k(
    const TA* __restrict__ A, const TB* __restrict__ B,
    const float* __restrict__ bias, TC* __restrict__ C,
    int M, int N, int K)
{
  __shared__ short sA[128][40];   // [m][k], +8 pad (row stride 80B, 16B-aligned)
  __shared__ short sBt[128][40];  // [n][k] (B transposed)

  const int t = threadIdx.x;
  const int lane = t & 63, w = t >> 6;
  const int quad = lane >> 4, l16 = lane & 15;
  const int wr = w >> 1, wc = w & 1;
  const int mbase = blockIdx.y * 128, nbase = blockIdx.x * 128;

  f32x4 acc[4][4];
#pragma unroll
  for (int i = 0; i < 4; ++i)
#pragma unroll
    for (int j = 0; j < 4; ++j)
      acc[i][j] = (f32x4){0.f, 0.f, 0.f, 0.f};

  for (int kb = 0; kb < K; kb += 32) {
    __syncthreads();
    // stage A tile 128x32
#pragma unroll
    for (int r = 0; r < 2; ++r) {
      int idx = t + 256 * r;
      int row = idx >> 2;
      int colc = (idx & 3) * 8;
      union { uint4 v; ushort s[8]; } u;
      fetch8(&A[(size_t)(mbase + row) * K + kb + colc], u.s);
      *(uint4*)&sA[row][colc] = u.v;
    }
    // stage B tile 32x128, transposed into sBt[n][k]
#pragma unroll
    for (int r = 0; r < 2; ++r) {
      int idx = t + 256 * r;
      int krow = idx & 31;
      int colc = (idx >> 5) * 8;
      ushort vals[8];
      fetch8(&B[(size_t)(kb + krow) * N + nbase + colc], vals);
#pragma unroll
      for (int jj = 0; jj < 8; ++jj) sBt[colc + jj][krow] = (short)vals[jj];
    }
    __syncthreads();

    bf16x8 af[4], bfr[4];
#pragma unroll
    for (int mt = 0; mt < 4; ++mt)
      af[mt] = *(const bf16x8*)&sA[wr * 64 + mt * 16 + l16][quad * 8];
#pragma unroll
    for (int nt = 0; nt < 4; ++nt)
      bfr[nt] = *(const bf16x8*)&sBt[wc * 64 + nt * 16 + l16][quad * 8];
#pragma unroll
    for (int mt = 0; mt < 4; ++mt)
#pragma unroll
      for (int nt = 0; nt < 4; ++nt)
        acc[mt][nt] = __builtin_amdgcn_mfma_f32_16x16x32_bf16(
            af[mt], bfr[nt], acc[mt][nt], 0, 0, 0);
  }

#pragma unroll
  for (int mt = 0; mt < 4; ++mt) {
#pragma unroll
    for (int nt = 0; nt < 4; ++nt) {
      int col = nbase + wc * 64 + nt * 16 + l16;
      float bv = bias ? bias[col] : 0.f;
#pragma unroll
      for (int ri = 0; ri < 4; ++ri) {
        int row = mbase + wr * 64 + mt * 16 + quad * 4 + ri;
        float val = acc[mt][nt][ri] + bv;
        if constexpr (std::is_same<TC, float>::value)
          C[(size_t)row * N + col] = val;
        else
          C[(size_t)row * N + col] = f32_to_bf16(val);
      }
    }
  }
}

// ---------------------------------------------------------------------------
// Flash-style strided-mask attention over bf16 qkv workspace.
// Grid: (n/64 q-tiles, b*h). Block: 256 threads; wave w owns 16 Q rows.
// Mask (reference polarity): (i >= j) && ((i-j) % 32 == 0)  ->  -inf
// ---------------------------------------------------------------------------
#define N_SEQ 2048
#define QKV_LD 3072
#define INNER 1024

__global__ __launch_bounds__(256) void attn_kernel(
    const ushort* __restrict__ qkv, ushort* __restrict__ attn_out)
{
  __shared__ short sK[64][72];    // [kv][dim]
  __shared__ short sVt[64][72];   // [dim][kv]  (transposed for B-fragments)
  __shared__ short sP[4][16][72]; // per-wave P re-layout buffer

  const int t = threadIdx.x;
  const int lane = t & 63, w = t >> 6;
  const int quad = lane >> 4, l16 = lane & 15;
  const int bh = blockIdx.y;
  const int b = bh >> 4, h = bh & 15;
  const int qbase = blockIdx.x * 64;
  const float scale = 0.03125f;  // 1024^-0.5
  const float NEG_INF = -__builtin_inff();

  // Q fragments in A-operand layout: m = l16 (q-row), k = quad*8+j
  const size_t qrowoff =
      ((size_t)(b * N_SEQ + qbase + w * 16 + l16)) * QKV_LD + h * 64;
  bf16x8 qf[2];
#pragma unroll
  for (int c = 0; c < 2; ++c)
    qf[c] = *(const bf16x8*)&qkv[qrowoff + 32 * c + quad * 8];

  f32x4 oacc[4];
#pragma unroll
  for (int dtile = 0; dtile < 4; ++dtile)
    oacc[dtile] = (f32x4){0.f, 0.f, 0.f, 0.f};
  float m_run[4], l_run[4];
#pragma unroll
  for (int ri = 0; ri < 4; ++ri) { m_run[ri] = NEG_INF; l_run[ri] = 0.f; }

  for (int kb = 0; kb < N_SEQ / 64; ++kb) {
    const int kvbase = kb * 64;
    __syncthreads();  // previous iteration's tiles fully consumed
    // stage K tile [64][64]
#pragma unroll
    for (int r = 0; r < 2; ++r) {
      int idx = t + 256 * r;
      int row = idx >> 3;
      int colc = (idx & 7) * 8;
      *(uint4*)&sK[row][colc] = *(const uint4*)&qkv[
          (size_t)(b * N_SEQ + kvbase + row) * QKV_LD + 1024 + h * 64 + colc];
    }
    // stage V tile transposed -> sVt[dim][kv]
#pragma unroll
    for (int r = 0; r < 2; ++r) {
      int idx = t + 256 * r;
      int kvrow = idx & 63;
      int cchunk = idx >> 6;  // 0..7
      union { uint4 v; ushort s[8]; } u;
      u.v = *(const uint4*)&qkv[
          (size_t)(b * N_SEQ + kvbase + kvrow) * QKV_LD + 2048 + h * 64 + cchunk * 8];
#pragma unroll
      for (int jj = 0; jj < 8; ++jj) sVt[cchunk * 8 + jj][kvrow] = (short)u.s[jj];
    }
    __syncthreads();

    // S = Q K^T  (C/D layout: row = quad*4+ri (q), col = l16 (kv within nt))
    f32x4 s[4];
#pragma unroll
    for (int nt = 0; nt < 4; ++nt) s[nt] = (f32x4){0.f, 0.f, 0.f, 0.f};
#pragma unroll
    for (int nt = 0; nt < 4; ++nt)
#pragma unroll
      for (int c = 0; c < 2; ++c) {
        bf16x8 kf = *(const bf16x8*)&sK[nt * 16 + l16][32 * c + quad * 8];
        s[nt] = __builtin_amdgcn_mfma_f32_16x16x32_bf16(qf[c], kf, s[nt], 0, 0, 0);
      }

    // scale + strided mask + per-row tile max
    float tmax[4] = {NEG_INF, NEG_INF, NEG_INF, NEG_INF};
#pragma unroll
    for (int nt = 0; nt < 4; ++nt) {
      int jg = kvbase + nt * 16 + l16;
#pragma unroll
      for (int ri = 0; ri < 4; ++ri) {
        int ig = qbase + w * 16 + quad * 4 + ri;
        float v = s[nt][ri] * scale;
        int d = ig - jg;
        if (d >= 0 && (d & 31) == 0) v = NEG_INF;
        s[nt][ri] = v;
        tmax[ri] = fmaxf(tmax[ri], v);
      }
    }
#pragma unroll
    for (int off = 1; off < 16; off <<= 1)
#pragma unroll
      for (int ri = 0; ri < 4; ++ri)
        tmax[ri] = fmaxf(tmax[ri], __shfl_xor(tmax[ri], off));

    float alpha[4], rsum[4];
#pragma unroll
    for (int ri = 0; ri < 4; ++ri) {
      float mn = fmaxf(m_run[ri], tmax[ri]);
      alpha[ri] = __expf(m_run[ri] - mn);
      m_run[ri] = mn;
      rsum[ri] = 0.f;
    }
#pragma unroll
    for (int nt = 0; nt < 4; ++nt)
#pragma unroll
      for (int ri = 0; ri < 4; ++ri) {
        float p = __expf(s[nt][ri] - m_run[ri]);  // exp(-inf)=0 for masked
        s[nt][ri] = p;
        rsum[ri] += p;
      }
#pragma unroll
    for (int off = 1; off < 16; off <<= 1)
#pragma unroll
      for (int ri = 0; ri < 4; ++ri)
        rsum[ri] += __shfl_xor(rsum[ri], off);
#pragma unroll
    for (int ri = 0; ri < 4; ++ri)
      l_run[ri] = l_run[ri] * alpha[ri] + rsum[ri];
#pragma unroll
    for (int dtile = 0; dtile < 4; ++dtile)
#pragma unroll
      for (int ri = 0; ri < 4; ++ri)
        oacc[dtile][ri] *= alpha[ri];

    // P: C-layout -> LDS -> A-layout (wave-local)
#pragma unroll
    for (int nt = 0; nt < 4; ++nt)
#pragma unroll
      for (int ri = 0; ri < 4; ++ri)
        sP[w][quad * 4 + ri][nt * 16 + l16] = (short)f32_to_bf16(s[nt][ri]);

#pragma unroll
    for (int c = 0; c < 2; ++c) {
      bf16x8 pf = *(const bf16x8*)&sP[w][l16][32 * c + quad * 8];
#pragma unroll
      for (int dtile = 0; dtile < 4; ++dtile) {
        bf16x8 vf = *(const bf16x8*)&sVt[dtile * 16 + l16][32 * c + quad * 8];
        oacc[dtile] = __builtin_amdgcn_mfma_f32_16x16x32_bf16(pf, vf, oacc[dtile], 0, 0, 0);
      }
    }
  }

  // epilogue: O / l, store bf16 [b, n, h*hd]
#pragma unroll
  for (int dtile = 0; dtile < 4; ++dtile)
#pragma unroll
    for (int ri = 0; ri < 4; ++ri) {
      int ig = qbase + w * 16 + quad * 4 + ri;
      float o = oacc[dtile][ri] / l_run[ri];
      attn_out[(size_t)(b * N_SEQ + ig) * INNER + h * 64 + dtile * 16 + l16] =
          f32_to_bf16(o);
    }
}

// ---------------------------------------------------------------------------
extern "C" void kernel_launch(void* const* d_in, const int* in_sizes, int n_in,
                              void* d_out, int out_size, void* d_ws, size_t ws_size,
                              hipStream_t stream) {
  const float* x    = (const float*)d_in[0];  // [2,2048,1024] fp32
  const float* Wqkv = (const float*)d_in[1];  // [1024,3072]  fp32
  const float* Wout = (const float*)d_in[2];  // [1024,1024]  fp32
  const float* bout = (const float*)d_in[3];  // [1024]       fp32
  float* out = (float*)d_out;                 // [2,2048,1024] fp32

  ushort* qkv  = (ushort*)d_ws;                  // 4096*3072 bf16 = 25.2 MB
  ushort* attn = qkv + (size_t)4096 * 3072;      // 4096*1024 bf16 = 8.4 MB

  // qkv = bf16(x) @ bf16(W_qkv), stored bf16
  gemm_k<float, float, ushort><<<dim3(3072 / 128, 4096 / 128), 256, 0, stream>>>(
      x, Wqkv, nullptr, qkv, 4096, 3072, 1024);
  // attention (bf16 in/out workspace)
  attn_kernel<<<dim3(N_SEQ / 64, 32), 256, 0, stream>>>(qkv, attn);
  // out = attn @ bf16(W_out) + b_out, stored fp32
  gemm_k<ushort, float, float><<<dim3(1024 / 128, 4096 / 128), 256, 0, stream>>>(
      attn, Wout, bout, out, 4096, 1024, 1024);
}

// Round 3
// 238.236 us; speedup vs baseline: 1.3779x; 1.3779x over previous
//
#include <hip/hip_runtime.h>

typedef __attribute__((ext_vector_type(8))) short bf16x8;
typedef __attribute__((ext_vector_type(4))) float f32x4;

__device__ __forceinline__ ushort f32_to_bf16(float f) {
  union { float f; unsigned u; } x; x.f = f;
  unsigned r = x.u + 0x7fffu + ((x.u >> 16) & 1u);
  return (ushort)(r >> 16);
}

// async global->LDS, 16B per lane; lds base must be wave-uniform
__device__ __forceinline__ void load16_to_lds(const void* g, void* l) {
  __builtin_amdgcn_global_load_lds(
      (const __attribute__((address_space(1))) unsigned int*)(
          reinterpret_cast<uintptr_t>(g)),
      (__attribute__((address_space(3))) unsigned int*)(
          reinterpret_cast<uintptr_t>(l)),
      16, 0, 0);
}

// ---------------------------------------------------------------------------
// convert fp32 -> bf16, 8 elems/thread
// ---------------------------------------------------------------------------
__global__ __launch_bounds__(256) void convert_bf16(
    const float* __restrict__ in, ushort* __restrict__ out, int n8)
{
  int i = blockIdx.x * 256 + threadIdx.x;
  if (i >= n8) return;
  const float4* p = (const float4*)(in + (size_t)i * 8);
  float4 a = p[0], b = p[1];
  union { uint4 v; ushort s[8]; } u;
  u.s[0] = f32_to_bf16(a.x); u.s[1] = f32_to_bf16(a.y);
  u.s[2] = f32_to_bf16(a.z); u.s[3] = f32_to_bf16(a.w);
  u.s[4] = f32_to_bf16(b.x); u.s[5] = f32_to_bf16(b.y);
  u.s[6] = f32_to_bf16(b.z); u.s[7] = f32_to_bf16(b.w);
  *(uint4*)(out + (size_t)i * 8) = u.v;
}

// ---------------------------------------------------------------------------
// transpose + convert: out[c][r] = bf16(in[r][c]); 32x32 LDS tiles
// ---------------------------------------------------------------------------
__global__ __launch_bounds__(256) void transpose_bf16(
    const float* __restrict__ in, ushort* __restrict__ out, int R, int C)
{
  __shared__ ushort tile[32][33];
  int t = threadIdx.x, tx = t & 31, ty = t >> 5;
  int rb = blockIdx.y * 32, cb = blockIdx.x * 32;
#pragma unroll
  for (int k = 0; k < 4; ++k)
    tile[ty + 8 * k][tx] = f32_to_bf16(in[(size_t)(rb + ty + 8 * k) * C + cb + tx]);
  __syncthreads();
#pragma unroll
  for (int k = 0; k < 4; ++k)
    out[(size_t)(cb + ty + 8 * k) * R + rb + tx] = tile[tx][ty + 8 * k];
}

// ---------------------------------------------------------------------------
// GEMM: C[M,N] = A[M,K] * Bt[N,K]^T (+ fp32 bias). bf16 in, fp32 accum.
// m97 structure: 128x128 tile, BK=32, global_load_lds width-16 staging.
// ---------------------------------------------------------------------------
template <typename TC>
__global__ __launch_bounds__(256) void gemm_bt(
    const ushort* __restrict__ A, const ushort* __restrict__ Bt,
    const float* __restrict__ bias, TC* __restrict__ C,
    int M, int N, int K)
{
  __shared__ ushort sA[128 * 32];  // [m][k] rows of 64B, contiguous (no pad)
  __shared__ ushort sB[128 * 32];  // [n][k]

  const int t = threadIdx.x;
  const int lane = t & 63, w = t >> 6;
  const int quad = lane >> 4, l16 = lane & 15;
  const int wr = w >> 1, wc = w & 1;
  const int mbase = blockIdx.y * 128, nbase = blockIdx.x * 128;
  const int lrow = lane >> 2, lchunk = (lane & 3) * 8;

  f32x4 acc[4][4];
#pragma unroll
  for (int i = 0; i < 4; ++i)
#pragma unroll
    for (int j = 0; j < 4; ++j)
      acc[i][j] = (f32x4){0.f, 0.f, 0.f, 0.f};

  for (int kb = 0; kb < K; kb += 32) {
    __syncthreads();
#pragma unroll
    for (int r = 0; r < 2; ++r) {
      int rb = w * 32 + r * 16;  // 16 rows (1KB) per wave-op
      load16_to_lds(&A[(size_t)(mbase + rb + lrow) * K + kb + lchunk], &sA[rb * 32]);
      load16_to_lds(&Bt[(size_t)(nbase + rb + lrow) * K + kb + lchunk], &sB[rb * 32]);
    }
    __syncthreads();  // drains vmcnt

    bf16x8 af[4], bf[4];
#pragma unroll
    for (int mt = 0; mt < 4; ++mt)
      af[mt] = *(const bf16x8*)&sA[(wr * 64 + mt * 16 + l16) * 32 + quad * 8];
#pragma unroll
    for (int nt = 0; nt < 4; ++nt)
      bf[nt] = *(const bf16x8*)&sB[(wc * 64 + nt * 16 + l16) * 32 + quad * 8];
#pragma unroll
    for (int mt = 0; mt < 4; ++mt)
#pragma unroll
      for (int nt = 0; nt < 4; ++nt)
        acc[mt][nt] = __builtin_amdgcn_mfma_f32_16x16x32_bf16(
            af[mt], bf[nt], acc[mt][nt], 0, 0, 0);
  }

#pragma unroll
  for (int mt = 0; mt < 4; ++mt) {
#pragma unroll
    for (int nt = 0; nt < 4; ++nt) {
      int col = nbase + wc * 64 + nt * 16 + l16;
      float bv = bias ? bias[col] : 0.f;
#pragma unroll
      for (int ri = 0; ri < 4; ++ri) {
        int row = mbase + wr * 64 + mt * 16 + quad * 4 + ri;
        float val = acc[mt][nt][ri] + bv;
        if constexpr (__is_same(TC, float))
          C[(size_t)row * N + col] = val;
        else
          C[(size_t)row * N + col] = f32_to_bf16(val);
      }
    }
  }
}

// ---------------------------------------------------------------------------
// Flash attention, S^T formulation, no-max softmax (logits bounded ~|1|).
// S^T = K*Q^T: A=K frag (m=j), B=Q frag (n=i).  C-layout: lane holds
// j = mt*16+quad*4+ri, i = l16  -> P packs 4 bf16 along j per lane (b64 write).
// Mask: (i>=j) && ((i-j)%32==0) -> 0, i.e. ((uint)(i-j) & 0x8000001F)==0.
// ---------------------------------------------------------------------------
#define N_SEQ 2048
#define QKV_LD 3072
#define INNER 1024

__global__ __launch_bounds__(256) void attn_kernel(
    const ushort* __restrict__ qkv, ushort* __restrict__ attn_out)
{
  __shared__ ushort sK[64][72];      // [kv][dim]
  __shared__ ushort sVt[64][72];     // [dim][kv]
  __shared__ ushort sPt[4][16][72];  // per-wave: [i][j]

  const int t = threadIdx.x;
  const int lane = t & 63, w = t >> 6;
  const int quad = lane >> 4, l16 = lane & 15;
  const int bh = blockIdx.y;
  const int b = bh >> 4, h = bh & 15;
  const int qbase = blockIdx.x * 64;
  const float scale = 0.03125f;  // 1024^-0.5

  const int i_row = qbase + w * 16 + l16;  // q row this lane owns (B-operand n)

  // Q fragment (B-operand): n = l16 (q-row), k = quad*8+j
  const size_t qrowoff = ((size_t)(b * N_SEQ + i_row)) * QKV_LD + h * 64;
  bf16x8 qf[2];
#pragma unroll
  for (int c = 0; c < 2; ++c)
    qf[c] = *(const bf16x8*)&qkv[qrowoff + 32 * c + quad * 8];

  f32x4 oacc[4];
#pragma unroll
  for (int dt = 0; dt < 4; ++dt) oacc[dt] = (f32x4){0.f, 0.f, 0.f, 0.f};
  float l_run = 0.f;

  for (int kb = 0; kb < N_SEQ / 64; ++kb) {
    const int kvbase = kb * 64;
    __syncthreads();
    // stage K tile [kv][dim]
#pragma unroll
    for (int r = 0; r < 2; ++r) {
      int idx = t + 256 * r;
      int row = idx >> 3;
      int colc = (idx & 7) * 8;
      *(uint4*)&sK[row][colc] = *(const uint4*)&qkv[
          (size_t)(b * N_SEQ + kvbase + row) * QKV_LD + 1024 + h * 64 + colc];
    }
    // stage V transposed -> sVt[dim][kv]
#pragma unroll
    for (int r = 0; r < 2; ++r) {
      int idx = t + 256 * r;
      int kvrow = idx & 63;
      int cchunk = idx >> 6;
      union { uint4 v; ushort s[8]; } u;
      u.v = *(const uint4*)&qkv[
          (size_t)(b * N_SEQ + kvbase + kvrow) * QKV_LD + 2048 + h * 64 + cchunk * 8];
#pragma unroll
      for (int jj = 0; jj < 8; ++jj) sVt[cchunk * 8 + jj][kvrow] = u.s[jj];
    }
    __syncthreads();

    // S^T = K Q^T
    f32x4 st[4];
#pragma unroll
    for (int mt = 0; mt < 4; ++mt) st[mt] = (f32x4){0.f, 0.f, 0.f, 0.f};
#pragma unroll
    for (int mt = 0; mt < 4; ++mt)
#pragma unroll
      for (int c = 0; c < 2; ++c) {
        bf16x8 kf = *(const bf16x8*)&sK[mt * 16 + l16][32 * c + quad * 8];
        st[mt] = __builtin_amdgcn_mfma_f32_16x16x32_bf16(kf, qf[c], st[mt], 0, 0, 0);
      }

    // exp (no max), mask, pack P (round-half-up via +0x8000 then byte-perm)
#pragma unroll
    for (int mt = 0; mt < 4; ++mt) {
      unsigned pb[4];
#pragma unroll
      for (int ri = 0; ri < 4; ++ri) {
        int j = kvbase + mt * 16 + quad * 4 + ri;
        unsigned d = (unsigned)(i_row - j);
        float p = __expf(st[mt][ri] * scale);
        p = ((d & 0x8000001Fu) == 0u) ? 0.f : p;
        l_run += p;
        union { float f; unsigned u; } cv; cv.f = p;
        pb[ri] = cv.u + 0x8000u;
      }
      unsigned lo = __builtin_amdgcn_perm(pb[1], pb[0], 0x07060302u);
      unsigned hi = __builtin_amdgcn_perm(pb[3], pb[2], 0x07060302u);
      *(uint2*)&sPt[w][l16][mt * 16 + quad * 4] = make_uint2(lo, hi);
    }

    // O += P V   (A = P: m=i, k=j;  B = V^T: n=d, k=j)
#pragma unroll
    for (int c2 = 0; c2 < 2; ++c2) {
      bf16x8 pf = *(const bf16x8*)&sPt[w][l16][c2 * 32 + quad * 8];
#pragma unroll
      for (int dt = 0; dt < 4; ++dt) {
        bf16x8 vf = *(const bf16x8*)&sVt[dt * 16 + l16][c2 * 32 + quad * 8];
        oacc[dt] = __builtin_amdgcn_mfma_f32_16x16x32_bf16(pf, vf, oacc[dt], 0, 0, 0);
      }
    }
  }

  // epilogue: reduce l across quads (lanes l16, l16+16, +32, +48)
  float l_red = l_run + __shfl_xor(l_run, 16);
  l_red += __shfl_xor(l_red, 32);

#pragma unroll
  for (int ri = 0; ri < 4; ++ri) {
    float lr = __shfl(l_red, quad * 4 + ri);  // lane quad*4+ri holds row i=quad*4+ri
    float inv = 1.0f / lr;
    int ig = qbase + w * 16 + quad * 4 + ri;
#pragma unroll
    for (int dt = 0; dt < 4; ++dt)
      attn_out[(size_t)(b * N_SEQ + ig) * INNER + h * 64 + dt * 16 + l16] =
          f32_to_bf16(oacc[dt][ri] * inv);
  }
}

// ---------------------------------------------------------------------------
extern "C" void kernel_launch(void* const* d_in, const int* in_sizes, int n_in,
                              void* d_out, int out_size, void* d_ws, size_t ws_size,
                              hipStream_t stream) {
  const float* x    = (const float*)d_in[0];  // [2,2048,1024] fp32
  const float* Wqkv = (const float*)d_in[1];  // [1024,3072]
  const float* Wout = (const float*)d_in[2];  // [1024,1024]
  const float* bout = (const float*)d_in[3];  // [1024]
  float* out = (float*)d_out;                 // [2,2048,1024] fp32

  ushort* qkv   = (ushort*)d_ws;                     // 4096*3072 = 24 MiB
  ushort* xb    = qkv + (size_t)4096 * 3072;         // 8 MiB (reused as attnb)
  ushort* wT    = xb + (size_t)4096 * 1024;          // 6 MiB (WqkvT, then WoutT)
  ushort* attnb = xb;                                // xb dead after GEMM1

  // x -> bf16
  convert_bf16<<<(4096 * 1024 / 8 + 255) / 256, 256, 0, stream>>>(
      x, xb, 4096 * 1024 / 8);
  // W_qkv^T -> bf16 [3072][1024]
  transpose_bf16<<<dim3(3072 / 32, 1024 / 32), 256, 0, stream>>>(
      Wqkv, wT, 1024, 3072);
  // qkv = xb @ WqkvT^T
  gemm_bt<ushort><<<dim3(3072 / 128, 4096 / 128), 256, 0, stream>>>(
      xb, wT, nullptr, qkv, 4096, 3072, 1024);
  // attention
  attn_kernel<<<dim3(N_SEQ / 64, 32), 256, 0, stream>>>(qkv, attnb);
  // W_out^T -> bf16 [1024][1024]
  transpose_bf16<<<dim3(1024 / 32, 1024 / 32), 256, 0, stream>>>(
      Wout, wT, 1024, 1024);
  // out = attnb @ WoutT^T + b_out (fp32 store)
  gemm_bt<float><<<dim3(1024 / 128, 4096 / 128), 256, 0, stream>>>(
      attnb, wT, bout, out, 4096, 1024, 1024);
}

// Round 4
// 204.046 us; speedup vs baseline: 1.6088x; 1.1676x over previous
//
#include <hip/hip_runtime.h>

typedef __attribute__((ext_vector_type(8))) short bf16x8;
typedef __attribute__((ext_vector_type(4))) float f32x4;

#if __has_builtin(__builtin_amdgcn_exp2f)
#define EXP2F(x) __builtin_amdgcn_exp2f(x)
#else
extern "C" __device__ float __ocml_native_exp2_f32(float);
#define EXP2F(x) __ocml_native_exp2_f32(x)
#endif

__device__ __forceinline__ ushort f32_to_bf16(float f) {
  union { float f; unsigned u; } x; x.f = f;
  unsigned r = x.u + 0x7fffu + ((x.u >> 16) & 1u);
  return (ushort)(r >> 16);
}

// async global->LDS, 16B per lane; lds base must be wave-uniform
__device__ __forceinline__ void load16_to_lds(const void* g, void* l) {
  __builtin_amdgcn_global_load_lds(
      (const __attribute__((address_space(1))) unsigned int*)(
          reinterpret_cast<uintptr_t>(g)),
      (__attribute__((address_space(3))) unsigned int*)(
          reinterpret_cast<uintptr_t>(l)),
      16, 0, 0);
}

// ---------------------------------------------------------------------------
// convert fp32 -> bf16, 8 elems/thread
// ---------------------------------------------------------------------------
__global__ __launch_bounds__(256) void convert_bf16(
    const float* __restrict__ in, ushort* __restrict__ out, int n8)
{
  int i = blockIdx.x * 256 + threadIdx.x;
  if (i >= n8) return;
  const float4* p = (const float4*)(in + (size_t)i * 8);
  float4 a = p[0], b = p[1];
  union { uint4 v; ushort s[8]; } u;
  u.s[0] = f32_to_bf16(a.x); u.s[1] = f32_to_bf16(a.y);
  u.s[2] = f32_to_bf16(a.z); u.s[3] = f32_to_bf16(a.w);
  u.s[4] = f32_to_bf16(b.x); u.s[5] = f32_to_bf16(b.y);
  u.s[6] = f32_to_bf16(b.z); u.s[7] = f32_to_bf16(b.w);
  *(uint4*)(out + (size_t)i * 8) = u.v;
}

// ---------------------------------------------------------------------------
// transpose + convert + optional per-column scale (cols < qcols get *qscale)
// ---------------------------------------------------------------------------
__global__ __launch_bounds__(256) void transpose_w(
    const float* __restrict__ in, ushort* __restrict__ out, int R, int C,
    int qcols, float qscale)
{
  __shared__ ushort tile[32][33];
  int t = threadIdx.x, tx = t & 31, ty = t >> 5;
  int rb = blockIdx.y * 32, cb = blockIdx.x * 32;
  float s = (cb + tx) < qcols ? qscale : 1.0f;
#pragma unroll
  for (int k = 0; k < 4; ++k)
    tile[ty + 8 * k][tx] =
        f32_to_bf16(in[(size_t)(rb + ty + 8 * k) * C + cb + tx] * s);
  __syncthreads();
#pragma unroll
  for (int k = 0; k < 4; ++k)
    out[(size_t)(cb + ty + 8 * k) * R + rb + tx] = tile[tx][ty + 8 * k];
}

// ---------------------------------------------------------------------------
// GEMM: A[M,K] * Bt[N,K]^T. bf16 in, fp32 accum. 128x128 tile, BK=32,
// global_load_lds staging. MODE 0: C fp32 + bias (LD=N).
// MODE 1 (qkv): col<2048 -> qk bf16 [M][2048]; col>=2048 -> Vt[bh][d][n] bf16.
// ---------------------------------------------------------------------------
template <int MODE, typename TC>
__global__ __launch_bounds__(256) void gemm_bt(
    const ushort* __restrict__ A, const ushort* __restrict__ Bt,
    const float* __restrict__ bias, TC* __restrict__ C,
    ushort* __restrict__ Vt, int M, int N, int K)
{
  __shared__ ushort sA[128 * 32];
  __shared__ ushort sB[128 * 32];

  const int t = threadIdx.x;
  const int lane = t & 63, w = t >> 6;
  const int quad = lane >> 4, l16 = lane & 15;
  const int wr = w >> 1, wc = w & 1;
  const int mbase = blockIdx.y * 128, nbase = blockIdx.x * 128;
  const int lrow = lane >> 2, lchunk = (lane & 3) * 8;

  f32x4 acc[4][4];
#pragma unroll
  for (int i = 0; i < 4; ++i)
#pragma unroll
    for (int j = 0; j < 4; ++j)
      acc[i][j] = (f32x4){0.f, 0.f, 0.f, 0.f};

  for (int kb = 0; kb < K; kb += 32) {
    __syncthreads();
#pragma unroll
    for (int r = 0; r < 2; ++r) {
      int rb = w * 32 + r * 16;
      load16_to_lds(&A[(size_t)(mbase + rb + lrow) * K + kb + lchunk], &sA[rb * 32]);
      load16_to_lds(&Bt[(size_t)(nbase + rb + lrow) * K + kb + lchunk], &sB[rb * 32]);
    }
    __syncthreads();

    bf16x8 af[4], bf[4];
#pragma unroll
    for (int mt = 0; mt < 4; ++mt)
      af[mt] = *(const bf16x8*)&sA[(wr * 64 + mt * 16 + l16) * 32 + quad * 8];
#pragma unroll
    for (int nt = 0; nt < 4; ++nt)
      bf[nt] = *(const bf16x8*)&sB[(wc * 64 + nt * 16 + l16) * 32 + quad * 8];
#pragma unroll
    for (int mt = 0; mt < 4; ++mt)
#pragma unroll
      for (int nt = 0; nt < 4; ++nt)
        acc[mt][nt] = __builtin_amdgcn_mfma_f32_16x16x32_bf16(
            af[mt], bf[nt], acc[mt][nt], 0, 0, 0);
  }

#pragma unroll
  for (int mt = 0; mt < 4; ++mt) {
#pragma unroll
    for (int nt = 0; nt < 4; ++nt) {
      int col = nbase + wc * 64 + nt * 16 + l16;
      if constexpr (MODE == 0) {
        float bv = bias ? bias[col] : 0.f;
#pragma unroll
        for (int ri = 0; ri < 4; ++ri) {
          int row = mbase + wr * 64 + mt * 16 + quad * 4 + ri;
          C[(size_t)row * N + col] = acc[mt][nt][ri] + bv;
        }
      } else {
        if (col < 2048) {
#pragma unroll
          for (int ri = 0; ri < 4; ++ri) {
            int row = mbase + wr * 64 + mt * 16 + quad * 4 + ri;
            C[(size_t)row * 2048 + col] = (TC)f32_to_bf16(acc[mt][nt][ri]);
          }
        } else {
          int hh = (col - 2048) >> 6, dd = (col - 2048) & 63;
#pragma unroll
          for (int ri = 0; ri < 4; ++ri) {
            int row = mbase + wr * 64 + mt * 16 + quad * 4 + ri;
            int bb = row >> 11, nn = row & 2047;
            Vt[((size_t)((bb * 16 + hh) * 64 + dd)) * 2048 + nn] =
                f32_to_bf16(acc[mt][nt][ri]);
          }
        }
      }
    }
  }
}

// ---------------------------------------------------------------------------
// Flash attention, S^T formulation; Q pre-scaled by scale*log2e (baked into
// W_qkv), so P = exp2(S') directly. l from MFMA with ones-B. Mask pattern is
// kb-invariant (precomputed per-lane AND masks); d>=0 boundary is a
// wave-uniform 3-way branch. K/V tiles: unpadded 64x64, XOR-chunk-swizzled,
// staged with global_load_lds. 4 waves x 32 q-rows = 128-row Q blocks.
// ---------------------------------------------------------------------------
#define NS 2048

__global__ __launch_bounds__(256) void attn_kernel(
    const ushort* __restrict__ qk, const ushort* __restrict__ vt,
    ushort* __restrict__ attn_out)
{
  __shared__ ushort sK[64 * 64];     // [kv][d] chunk-swizzled
  __shared__ ushort sV[64 * 64];     // [d][kv] chunk-swizzled
  __shared__ ushort sPt[4][32][72];  // per-wave [i][j], +8 pad

  const int t = threadIdx.x;
  const int lane = t & 63, w = t >> 6;
  const int quad = lane >> 4, l16 = lane & 15;
  const int bh = blockIdx.y, b = bh >> 4, h = bh & 15;
  const int qbase = blockIdx.x * 128;
  const int rowK = lane >> 3;               // 0..7 within glds row-group
  const int csw = ((lane & 7) ^ rowK) * 8;  // swizzled chunk offset (elems)
  const int swz = (l16 & 7);                // read-side swizzle key

  // Q fragments (B-operand): n=l16 -> i, k=quad*8+j -> d
  bf16x8 qf[2][2];
#pragma unroll
  for (int is = 0; is < 2; ++is)
#pragma unroll
    for (int c = 0; c < 2; ++c)
      qf[is][c] = *(const bf16x8*)&qk[
          ((size_t)(b * NS + qbase + w * 32 + is * 16 + l16)) * 2048 +
          h * 64 + c * 32 + quad * 8];

  bf16x8 ones;
  { union { bf16x8 v; ushort s[8]; } ou;
#pragma unroll
    for (int i = 0; i < 8; ++i) ou.s[i] = 0x3F80;
    ones = ou.v; }

  // pattern masks: masked(is,mt,ri) <=> (i-j) % 32 == 0 (kb-invariant part)
  unsigned amask[2][4][2];
#pragma unroll
  for (int is = 0; is < 2; ++is)
#pragma unroll
    for (int mt = 0; mt < 4; ++mt)
#pragma unroll
      for (int hf = 0; hf < 2; ++hf) {
        int r0 = hf * 2, r1 = hf * 2 + 1;
        int base = is * 16 + l16 - mt * 16 - quad * 4;
        unsigned m = 0xFFFFFFFFu;
        if (((base - r0) & 31) == 0) m &= 0xFFFF0000u;
        if (((base - r1) & 31) == 0) m &= 0x0000FFFFu;
        amask[is][mt][hf] = m;
      }

  const int ib64 = (qbase + w * 32) >> 6;  // wave-uniform boundary kv-tile

  f32x4 oacc[2][4];
#pragma unroll
  for (int is = 0; is < 2; ++is)
#pragma unroll
    for (int dt = 0; dt < 4; ++dt) oacc[is][dt] = (f32x4){0.f, 0.f, 0.f, 0.f};
  f32x4 lsum[2];
  lsum[0] = (f32x4){0.f, 0.f, 0.f, 0.f};
  lsum[1] = (f32x4){0.f, 0.f, 0.f, 0.f};

  for (int kb = 0; kb < NS / 64; ++kb) {
    const int kvbase = kb * 64;
    __syncthreads();
    // stage K[kv][d] and V[d][kv] via global_load_lds (swizzled chunks)
#pragma unroll
    for (int g = 0; g < 2; ++g) {
      int rk = w * 16 + g * 8 + rowK;
      load16_to_lds(&qk[((size_t)(b * NS + kvbase + rk)) * 2048 + 1024 +
                        h * 64 + csw],
                    &sK[(w * 16 + g * 8) * 64]);
      load16_to_lds(&vt[((size_t)(bh * 64 + rk)) * 2048 + kvbase + csw],
                    &sV[(w * 16 + g * 8) * 64]);
    }
    __syncthreads();

    // S^T = K Q^T : per lane j = kvbase + mt*16 + quad*4 + ri, i-col = l16
    f32x4 st[2][4];
#pragma unroll
    for (int is = 0; is < 2; ++is)
#pragma unroll
      for (int mt = 0; mt < 4; ++mt) st[is][mt] = (f32x4){0.f, 0.f, 0.f, 0.f};
#pragma unroll
    for (int mt = 0; mt < 4; ++mt)
#pragma unroll
      for (int c = 0; c < 2; ++c) {
        bf16x8 kf = *(const bf16x8*)&sK[(mt * 16 + l16) * 64 +
                                        (((c * 4 + quad) ^ swz) * 8)];
        st[0][mt] = __builtin_amdgcn_mfma_f32_16x16x32_bf16(
            kf, qf[0][c], st[0][mt], 0, 0, 0);
        st[1][mt] = __builtin_amdgcn_mfma_f32_16x16x32_bf16(
            kf, qf[1][c], st[1][mt], 0, 0, 0);
      }

    // softmax (exp2 only) + pack to sPt
    if (kb < ib64) {  // fully past diagonal: precomputed pattern mask
#pragma unroll
      for (int is = 0; is < 2; ++is)
#pragma unroll
        for (int mt = 0; mt < 4; ++mt) {
          unsigned pb[4];
#pragma unroll
          for (int ri = 0; ri < 4; ++ri) {
            union { float f; unsigned u; } cv;
            cv.f = EXP2F(st[is][mt][ri]);
            pb[ri] = cv.u + 0x8000u;
          }
          unsigned lo = __builtin_amdgcn_perm(pb[1], pb[0], 0x07060302u) &
                        amask[is][mt][0];
          unsigned hi = __builtin_amdgcn_perm(pb[3], pb[2], 0x07060302u) &
                        amask[is][mt][1];
          *(uint2*)&sPt[w][is * 16 + l16][mt * 16 + quad * 4] =
              make_uint2(lo, hi);
        }
    } else if (kb > ib64) {  // above diagonal: no mask
#pragma unroll
      for (int is = 0; is < 2; ++is)
#pragma unroll
        for (int mt = 0; mt < 4; ++mt) {
          unsigned pb[4];
#pragma unroll
          for (int ri = 0; ri < 4; ++ri) {
            union { float f; unsigned u; } cv;
            cv.f = EXP2F(st[is][mt][ri]);
            pb[ri] = cv.u + 0x8000u;
          }
          unsigned lo = __builtin_amdgcn_perm(pb[1], pb[0], 0x07060302u);
          unsigned hi = __builtin_amdgcn_perm(pb[3], pb[2], 0x07060302u);
          *(uint2*)&sPt[w][is * 16 + l16][mt * 16 + quad * 4] =
              make_uint2(lo, hi);
        }
    } else {  // boundary tile: full per-element test
#pragma unroll
      for (int is = 0; is < 2; ++is) {
        int irow = qbase + w * 32 + is * 16 + l16;
#pragma unroll
        for (int mt = 0; mt < 4; ++mt) {
          unsigned pb[4];
#pragma unroll
          for (int ri = 0; ri < 4; ++ri) {
            int j = kvbase + mt * 16 + quad * 4 + ri;
            float p = EXP2F(st[is][mt][ri]);
            unsigned du = (unsigned)(irow - j);
            if ((du & 0x8000001Fu) == 0u) p = 0.f;
            union { float f; unsigned u; } cv; cv.f = p;
            pb[ri] = cv.u + 0x8000u;
          }
          unsigned lo = __builtin_amdgcn_perm(pb[1], pb[0], 0x07060302u);
          unsigned hi = __builtin_amdgcn_perm(pb[3], pb[2], 0x07060302u);
          *(uint2*)&sPt[w][is * 16 + l16][mt * 16 + quad * 4] =
              make_uint2(lo, hi);
        }
      }
    }

    // O += P V ; l += P * ones
#pragma unroll
    for (int c2 = 0; c2 < 2; ++c2) {
      bf16x8 vf[4];
#pragma unroll
      for (int dt = 0; dt < 4; ++dt)
        vf[dt] = *(const bf16x8*)&sV[(dt * 16 + l16) * 64 +
                                     (((c2 * 4 + quad) ^ swz) * 8)];
#pragma unroll
      for (int is = 0; is < 2; ++is) {
        bf16x8 pf = *(const bf16x8*)&sPt[w][is * 16 + l16][c2 * 32 + quad * 8];
        lsum[is] = __builtin_amdgcn_mfma_f32_16x16x32_bf16(
            pf, ones, lsum[is], 0, 0, 0);
#pragma unroll
        for (int dt = 0; dt < 4; ++dt)
          oacc[is][dt] = __builtin_amdgcn_mfma_f32_16x16x32_bf16(
              pf, vf[dt], oacc[is][dt], 0, 0, 0);
      }
    }
  }

  // epilogue: O / l
#pragma unroll
  for (int is = 0; is < 2; ++is)
#pragma unroll
    for (int ri = 0; ri < 4; ++ri) {
      float inv = __builtin_amdgcn_rcpf(lsum[is][ri]);
      int ig = qbase + w * 32 + is * 16 + quad * 4 + ri;
#pragma unroll
      for (int dt = 0; dt < 4; ++dt)
        attn_out[(size_t)(b * NS + ig) * 1024 + h * 64 + dt * 16 + l16] =
            f32_to_bf16(oacc[is][dt][ri] * inv);
    }
}

// ---------------------------------------------------------------------------
extern "C" void kernel_launch(void* const* d_in, const int* in_sizes, int n_in,
                              void* d_out, int out_size, void* d_ws, size_t ws_size,
                              hipStream_t stream) {
  const float* x    = (const float*)d_in[0];  // [2,2048,1024] fp32
  const float* Wqkv = (const float*)d_in[1];  // [1024,3072]
  const float* Wout = (const float*)d_in[2];  // [1024,1024]
  const float* bout = (const float*)d_in[3];  // [1024]
  float* out = (float*)d_out;                 // [2,2048,1024] fp32

  ushort* qkbuf = (ushort*)d_ws;                    // 4096*2048 = 16 MB
  ushort* Vt    = qkbuf + (size_t)4096 * 2048;      // 32*64*2048 = 8 MB
  ushort* xb    = Vt + (size_t)32 * 64 * 2048;      // 8 MB (reused as attnb)
  ushort* wT    = xb + (size_t)4096 * 1024;         // 6 MB
  ushort* attnb = xb;

  // qscale = log2(e) / 32, baked into Q columns of W_qkv
  const float QSCALE = 0.04508422002778011f;

  convert_bf16<<<2048, 256, 0, stream>>>(x, xb, 4096 * 1024 / 8);
  transpose_w<<<dim3(3072 / 32, 1024 / 32), 256, 0, stream>>>(
      Wqkv, wT, 1024, 3072, 1024, QSCALE);
  // qkv GEMM: writes qk [n][2048] + Vt [bh][d][n]
  gemm_bt<1, ushort><<<dim3(3072 / 128, 4096 / 128), 256, 0, stream>>>(
      xb, wT, nullptr, qkbuf, Vt, 4096, 3072, 1024);
  // attention
  attn_kernel<<<dim3(NS / 128, 32), 256, 0, stream>>>(qkbuf, Vt, attnb);
  transpose_w<<<dim3(1024 / 32, 1024 / 32), 256, 0, stream>>>(
      Wout, wT, 1024, 1024, 0, 1.0f);
  gemm_bt<0, float><<<dim3(1024 / 128, 4096 / 128), 256, 0, stream>>>(
      attnb, wT, bout, out, nullptr, 4096, 1024, 1024);
}